// Round 3
// baseline (162.951 us; speedup 1.0000x reference)
//
#include <hip/hip_runtime.h>
#include <math.h>

#define NPTS 4096
#define LDA  264          // bf16 row stride (16B-aligned, conflict-benign)
// LDS regions (bytes)
#define S_R1  0           // bf16 [67][LDA]: xT -> x1 -> xs -> y
#define S_R3  35376       // bf16 [64][LDA]: delta ; later f32 Ct[32][257]
#define S_BML 69168       // f32 [64][20]
#define S_CML 74288       // f32 [64][20]
#define SMEM_SZ 79408

typedef __bf16 bf16x8 __attribute__((ext_vector_type(8)));
typedef __bf16 bf16x4 __attribute__((ext_vector_type(4)));
typedef float  f32x4  __attribute__((ext_vector_type(4)));
typedef float  f32x2  __attribute__((ext_vector_type(2)));

// packed fp32 (CDNA full-rate, 2 f32 per issue slot)
#define PK_MUL(d, s0, s1)  asm("v_pk_mul_f32 %0, %1, %2" : "=v"(d) : "v"(s0), "v"(s1))
#define PK_FMA(d, s0, s2)  asm("v_pk_fma_f32 %0, %1, %0, %2" : "+v"(d) : "v"(s0), "v"(s2))   // d = s0*d + s2
#define PK_FMA3(d, s0, s1) asm("v_pk_fma_f32 %0, %1, %2, %0" : "+v"(d) : "v"(s0), "v"(s1))   // d += s0*s1
#define PK_ADD(d, s0, s1)  asm("v_pk_add_f32 %0, %1, %2" : "=v"(d) : "v"(s0), "v"(s1))

__device__ __forceinline__ float sigmoidf_(float v) {
  return __fdividef(1.f, 1.f + __expf(-v));
}
__device__ __forceinline__ bf16x8 cvt8(float4 v0, float4 v1) {
  bf16x8 r;
  r[0] = (__bf16)v0.x; r[1] = (__bf16)v0.y; r[2] = (__bf16)v0.z; r[3] = (__bf16)v0.w;
  r[4] = (__bf16)v1.x; r[5] = (__bf16)v1.y; r[6] = (__bf16)v1.z; r[7] = (__bf16)v1.w;
  return r;
}
__device__ __forceinline__ f32x2 lo2(float4 v) { f32x2 r; r[0] = v.x; r[1] = v.y; return r; }
__device__ __forceinline__ f32x2 hi2(float4 v) { f32x2 r; r[0] = v.z; r[1] = v.w; return r; }

// ===== fully fused single kernel. grid (128, 4), 512 threads, 79.4 KB dyn LDS (2 blk/CU).
__global__ __launch_bounds__(512, 4) void k_mega(const float* __restrict__ x,
                                                 const float* __restrict__ w_in,
                                                 const float* __restrict__ b_in,
                                                 const float* __restrict__ wconv,
                                                 const float* __restrict__ bconv,
                                                 const float* __restrict__ A_log,
                                                 const float* __restrict__ Dsk,
                                                 const float* __restrict__ Bw,
                                                 const float* __restrict__ Cw,
                                                 const float* __restrict__ w_out,
                                                 const float* __restrict__ b_out,
                                                 const float* __restrict__ gamma,
                                                 const float* __restrict__ beta,
                                                 float* __restrict__ out) {
  extern __shared__ unsigned char smem[];
  __bf16* R1  = (__bf16*)(smem + S_R1);
  __bf16* bdt = (__bf16*)(smem + S_R3);
  float*  Bml = (float*) (smem + S_BML);
  float*  Cml = (float*) (smem + S_CML);
  float*  Ct  = (float*) (smem + S_R3);   // aliases bdt (dead after scan)

  const int tid = threadIdx.x, lane = tid & 63, w = tid >> 6;
  const int b = blockIdx.y, t0 = blockIdx.x << 5;
  const int mrow = lane & 15, klane = (lane >> 4) << 3;
  const int r4 = (lane >> 4) << 2;

  // ---- early per-thread constants (independent of all phases; issued at top)
  const int ds = tid >> 1, sh = (tid & 1) << 3;       // scan mapping
  f32x2 a01, a23, a45, a67;
  {
    float4 A0 = *(const float4*)&A_log[(ds << 4) + sh];
    float4 A1 = *(const float4*)&A_log[(ds << 4) + sh + 4];
    a01[0] = -__expf(A0.x); a01[1] = -__expf(A0.y);
    a23[0] = -__expf(A0.z); a23[1] = -__expf(A0.w);
    a45[0] = -__expf(A1.x); a45[1] = -__expf(A1.y);
    a67[0] = -__expf(A1.z); a67[1] = -__expf(A1.w);
  }
  const float Dv = Dsk[ds];
  const int dcv = tid & 255;                          // conv channel
  const float4 wc = *(const float4*)&wconv[dcv << 2];
  const float bcv = bconv[dcv];
  float g[4], be[4];
  #pragma unroll
  for (int j = 0; j < 4; ++j) {
    g[j]  = gamma[lane + 64 * j];
    be[j] = beta[lane + 64 * j];
  }

  // ---- P1: transpose x[b, :, t0-35 .. t0+31] -> R1 rows 0..66 (row i <-> t = t0-35+i)
  {
    const int c = tid >> 1;
    const size_t xrow = (size_t)(b * 256 + c) * NPTS;
    #pragma unroll
    for (int r = 0; r < 8; ++r) {
      int q = (tid & 1) + (r << 1);
      int t = t0 - 32 + (q << 2);
      float4 v = make_float4(0.f, 0.f, 0.f, 0.f);
      if (t >= 0) v = *(const float4*)&x[xrow + t];
      int i0 = 3 + (q << 2);
      R1[(i0 + 0) * LDA + c] = (__bf16)v.x;
      R1[(i0 + 1) * LDA + c] = (__bf16)v.y;
      R1[(i0 + 2) * LDA + c] = (__bf16)v.z;
      R1[(i0 + 3) * LDA + c] = (__bf16)v.w;
    }
    if (tid < 256) {   // head rows 0..2 (t = t0-35..t0-33)
      int t = t0 - 36;
      float4 v = make_float4(0.f, 0.f, 0.f, 0.f);
      if (t >= 0) v = *(const float4*)&x[(size_t)(b * 256 + tid) * NPTS + t];
      R1[0 * LDA + tid] = (__bf16)v.y;
      R1[1 * LDA + tid] = (__bf16)v.z;
      R1[2 * LDA + tid] = (__bf16)v.w;
    }
  }
  // pre-issue P2's first A-tile (global, independent of LDS) before the barrier
  const float* wZ0 = &w_in[(size_t)(256 + (w << 5) + mrow) * 256 + klane];
  const float* wZ1 = wZ0 + 16 * 256;
  float4 z00 = *(const float4*)&wZ0[0], z01 = *(const float4*)&wZ0[4];
  float4 z10 = *(const float4*)&wZ1[0], z11 = *(const float4*)&wZ1[4];
  __syncthreads();

  // ---- P2: delta = sigmoid(Wz.x + bz): M 256..511, n-tiles {3,19,35,51} -> bdt[64][LDA]
  {
    f32x4 acc[2][4] = {};
    for (int k0 = 0; k0 < 256; k0 += 32) {
      bf16x8 af0 = cvt8(z00, z01), af1 = cvt8(z10, z11);
      int kn = (k0 + 32) & 255;
      z00 = *(const float4*)&wZ0[kn]; z01 = *(const float4*)&wZ0[kn + 4];
      z10 = *(const float4*)&wZ1[kn]; z11 = *(const float4*)&wZ1[kn + 4];
      #pragma unroll
      for (int ni = 0; ni < 4; ++ni) {
        bf16x8 bx = *(bf16x8*)&R1[(3 + (ni << 4) + mrow) * LDA + k0 + klane];
        acc[0][ni] = __builtin_amdgcn_mfma_f32_16x16x32_bf16(af0, bx, acc[0][ni], 0, 0, 0);
        acc[1][ni] = __builtin_amdgcn_mfma_f32_16x16x32_bf16(af1, bx, acc[1][ni], 0, 0, 0);
      }
    }
    #pragma unroll
    for (int mi = 0; mi < 2; ++mi) {
      int d = (w << 5) + (mi << 4) + r4;
      float4 bi = *(const float4*)&b_in[256 + d];
      float bia[4] = {bi.x, bi.y, bi.z, bi.w};
      #pragma unroll
      for (int ni = 0; ni < 4; ++ni) {
        int j = (ni << 4) + mrow;                 // row j <-> t = t0-32+j
        bool ok = (t0 - 32 + j) >= 0;
        bf16x4 p;
        #pragma unroll
        for (int rg = 0; rg < 4; ++rg)
          p[rg] = ok ? (__bf16)sigmoidf_(acc[mi][ni][rg] + bia[rg]) : (__bf16)0.f;
        *(bf16x4*)&bdt[j * LDA + d] = p;
      }
    }
  }

  // ---- P3: x1 = Wx.x + bx: M 0..255, n-tiles {0,16,32,48,51} -> R1 (in place after barrier)
  {
    const float* wX0 = &w_in[(size_t)((w << 5) + mrow) * 256 + klane];
    const float* wX1 = wX0 + 16 * 256;
    float4 x00 = *(const float4*)&wX0[0], x01 = *(const float4*)&wX0[4];
    float4 x10 = *(const float4*)&wX1[0], x11 = *(const float4*)&wX1[4];
    f32x4 acc[2][5] = {};
    const int n0s[5] = {0, 16, 32, 48, 51};
    for (int k0 = 0; k0 < 256; k0 += 32) {
      bf16x8 af0 = cvt8(x00, x01), af1 = cvt8(x10, x11);
      int kn = (k0 + 32) & 255;
      x00 = *(const float4*)&wX0[kn]; x01 = *(const float4*)&wX0[kn + 4];
      x10 = *(const float4*)&wX1[kn]; x11 = *(const float4*)&wX1[kn + 4];
      #pragma unroll
      for (int ni = 0; ni < 5; ++ni) {
        bf16x8 bx = *(bf16x8*)&R1[(n0s[ni] + mrow) * LDA + k0 + klane];
        acc[0][ni] = __builtin_amdgcn_mfma_f32_16x16x32_bf16(af0, bx, acc[0][ni], 0, 0, 0);
        acc[1][ni] = __builtin_amdgcn_mfma_f32_16x16x32_bf16(af1, bx, acc[1][ni], 0, 0, 0);
      }
    }
    __syncthreads();   // all xT reads done -> R1 writable
    #pragma unroll
    for (int mi = 0; mi < 2; ++mi) {
      int d = (w << 5) + (mi << 4) + r4;
      float4 bi = *(const float4*)&b_in[d];
      float bia[4] = {bi.x, bi.y, bi.z, bi.w};
      #pragma unroll
      for (int ni = 0; ni < 5; ++ni) {
        int i = n0s[ni] + mrow;                   // rows 51..63 double-written, same value
        bool ok = (t0 - 35 + i) >= 0;
        bf16x4 p;
        #pragma unroll
        for (int rg = 0; rg < 4; ++rg) {
          float v = acc[mi][ni][rg] + bia[rg];
          p[rg] = ok ? (__bf16)v : (__bf16)0.f;
        }
        *(bf16x4*)&R1[i * LDA + d] = p;
      }
    }
  }
  __syncthreads();

  // pre-issue P5's first B/C weight tile (global) before the conv phase
  const int mat = w & 1, n0bc = (w >> 1) << 4;
  const float* WrBC = (mat ? Cw : Bw) + mrow * 256 + klane;
  float4 wv0 = *(const float4*)&WrBC[0], wv1 = *(const float4*)&WrBC[4];

  // ---- P4: conv + silu, in place with -3 row stagger, depth-1 prefetch of x window
  {
    const int d = dcv, half = tid >> 8;
    const int j0 = half << 5;
    float m3 = (float)R1[(j0 + 0) * LDA + d];
    float m2 = (float)R1[(j0 + 1) * LDA + d];
    float m1 = (float)R1[(j0 + 2) * LDA + d];
    float xc_n = (float)R1[(j0 + 3) * LDA + d];
    float d0 = 0.f, d1 = 0.f, d2 = 0.f;   // upper half defers rows 32..34 (seam race)
    #pragma unroll
    for (int i2 = 0; i2 < 32; ++i2) {
      float xc = xc_n;
      xc_n = (float)R1[(j0 + (i2 == 31 ? 34 : i2 + 4)) * LDA + d];  // folds at compile time
      float cv = fmaf(wc.x, m3, fmaf(wc.y, m2, fmaf(wc.z, m1, fmaf(wc.w, xc, bcv))));
      float sv = cv * sigmoidf_(cv);
      if (half && i2 == 0)      d0 = sv;
      else if (half && i2 == 1) d1 = sv;
      else if (half && i2 == 2) d2 = sv;
      else R1[(j0 + i2) * LDA + d] = (__bf16)sv;
      m3 = m2; m2 = m1; m1 = xc;
    }
    __syncthreads();
    if (half) {
      R1[32 * LDA + d] = (__bf16)d0;
      R1[33 * LDA + d] = (__bf16)d1;
      R1[34 * LDA + d] = (__bf16)d2;
    }
  }
  __syncthreads();

  // ---- P5: B/C projection, all 8 waves (w&1 = B/C, w>>1 = n-tile)
  {
    f32x4 accb = {};
    for (int k0 = 0; k0 < 256; k0 += 32) {
      bf16x8 av = cvt8(wv0, wv1);
      int kn = (k0 + 32) & 255;
      wv0 = *(const float4*)&WrBC[kn]; wv1 = *(const float4*)&WrBC[kn + 4];
      bf16x8 bv = *(bf16x8*)&R1[(n0bc + mrow) * LDA + k0 + klane];
      accb = __builtin_amdgcn_mfma_f32_16x16x32_bf16(av, bv, accb, 0, 0, 0);
    }
    float* dst = mat ? Cml : Bml;           // D: row=m=s, col=n=t
    int j = n0bc + mrow;
    #pragma unroll
    for (int rg = 0; rg < 4; ++rg)
      dst[j * 20 + r4 + rg] = accb[rg];
  }
  // pre-issue P7's first w_out tile (global, independent) before the scan
  const float* wO0 = &w_out[(size_t)((w << 5) + mrow) * 256 + klane];
  const float* wO1 = wO0 + 16 * 256;
  float4 o00 = *(const float4*)&wO0[0], o01 = *(const float4*)&wO0[4];
  float4 o10 = *(const float4*)&wO1[0], o11 = *(const float4*)&wO1[4];
  __syncthreads();

  // ---- P6: scan — 32 warm steps (h only), 32 live steps (y -> R1), packed-f32 math
  f32x2 h01 = {0.f, 0.f}, h23 = {0.f, 0.f}, h45 = {0.f, 0.f}, h67 = {0.f, 0.f};
  float u_n = (float)bdt[0 * LDA + ds];
  float4 b0_n = *(float4*)&Bml[0 * 20 + sh];
  float4 b1_n = *(float4*)&Bml[0 * 20 + sh + 4];
  #pragma unroll
  for (int j = 0; j < 32; ++j) {
    float u = u_n; float4 b0 = b0_n, b1 = b1_n;
    u_n = (float)bdt[(j + 1) * LDA + ds];          // j+1 <= 32: valid row
    b0_n = *(float4*)&Bml[(j + 1) * 20 + sh];
    b1_n = *(float4*)&Bml[(j + 1) * 20 + sh + 4];
    f32x2 u2; u2[0] = u; u2[1] = u;
    f32x2 t;
    PK_MUL(t, u2, lo2(b0)); PK_FMA(h01, a01, t);
    PK_MUL(t, u2, hi2(b0)); PK_FMA(h23, a23, t);
    PK_MUL(t, u2, lo2(b1)); PK_FMA(h45, a45, t);
    PK_MUL(t, u2, hi2(b1)); PK_FMA(h67, a67, t);
  }
  {
    float4 c0_n = *(float4*)&Cml[32 * 20 + sh];
    float4 c1_n = *(float4*)&Cml[32 * 20 + sh + 4];
    #pragma unroll
    for (int j = 32; j < 64; ++j) {
      float u = u_n; float4 b0 = b0_n, b1 = b1_n, c0 = c0_n, c1 = c1_n;
      int jn = (j + 1) & 63;                       // j=63 wraps to row 0 (harmless)
      u_n = (float)bdt[jn * LDA + ds];
      b0_n = *(float4*)&Bml[jn * 20 + sh];
      b1_n = *(float4*)&Bml[jn * 20 + sh + 4];
      c0_n = *(float4*)&Cml[jn * 20 + sh];
      c1_n = *(float4*)&Cml[jn * 20 + sh + 4];
      f32x2 u2; u2[0] = u; u2[1] = u;
      f32x2 t;
      PK_MUL(t, u2, lo2(b0)); PK_FMA(h01, a01, t);
      PK_MUL(t, u2, hi2(b0)); PK_FMA(h23, a23, t);
      PK_MUL(t, u2, lo2(b1)); PK_FMA(h45, a45, t);
      PK_MUL(t, u2, hi2(b1)); PK_FMA(h67, a67, t);
      f32x2 pa, pb, ps;
      PK_MUL(pa, h01, lo2(c0)); PK_FMA3(pa, h23, hi2(c0));
      PK_MUL(pb, h45, lo2(c1)); PK_FMA3(pb, h67, hi2(c1));
      PK_ADD(ps, pa, pb);
      float yv = ps[0] + ps[1];
      yv += __shfl_xor(yv, 1);
      if ((tid & 1) == 0) {
        float xv = (float)R1[j * LDA + ds];
        R1[j * LDA + ds] = (__bf16)fmaf(Dv, xv, yv);
      }
    }
  }
  __syncthreads();

  // ---- P7: out_proj MFMA on y (R1 rows 32..63) -> Ct (aliases dead bdt)
  float4 xv[4]; float bo4[4];
  {
    f32x4 acc[2][2] = {};
    for (int k0 = 0; k0 < 256; k0 += 32) {
      bf16x8 af0 = cvt8(o00, o01), af1 = cvt8(o10, o11);
      int kn = (k0 + 32) & 255;
      o00 = *(const float4*)&wO0[kn]; o01 = *(const float4*)&wO0[kn + 4];
      o10 = *(const float4*)&wO1[kn]; o11 = *(const float4*)&wO1[kn + 4];
      bf16x8 bx0 = *(bf16x8*)&R1[(32 + mrow) * LDA + k0 + klane];
      bf16x8 bx1 = *(bf16x8*)&R1[(48 + mrow) * LDA + k0 + klane];
      acc[0][0] = __builtin_amdgcn_mfma_f32_16x16x32_bf16(af0, bx0, acc[0][0], 0, 0, 0);
      acc[0][1] = __builtin_amdgcn_mfma_f32_16x16x32_bf16(af0, bx1, acc[0][1], 0, 0, 0);
      acc[1][0] = __builtin_amdgcn_mfma_f32_16x16x32_bf16(af1, bx0, acc[1][0], 0, 0, 0);
      acc[1][1] = __builtin_amdgcn_mfma_f32_16x16x32_bf16(af1, bx1, acc[1][1], 0, 0, 0);
    }
    // issue the residual x-gather early: lands while Ct is being written
    #pragma unroll
    for (int r = 0; r < 4; ++r) {
      int idx = (r << 9) + tid;
      int c = idx >> 3, t4 = (idx & 7) << 2;
      xv[r] = *(const float4*)&x[((size_t)(b * 256 + c)) * NPTS + t0 + t4];
      bo4[r] = b_out[c];
    }
    const int o0w = w << 5;
    #pragma unroll
    for (int mi = 0; mi < 2; ++mi)
      #pragma unroll
      for (int ni = 0; ni < 2; ++ni) {
        int t = (ni << 4) + mrow;
        int o = o0w + (mi << 4) + r4;
        #pragma unroll
        for (int rg = 0; rg < 4; ++rg)
          Ct[t * 257 + o + rg] = acc[mi][ni][rg];
      }
  }
  __syncthreads();

  // ---- P8: residual + bias, LayerNorm over C, transposed store
  #pragma unroll
  for (int r = 0; r < 4; ++r) {
    int idx = (r << 9) + tid;
    int c = idx >> 3, t4 = (idx & 7) << 2;
    Ct[(t4 + 0) * 257 + c] += xv[r].x + bo4[r];
    Ct[(t4 + 1) * 257 + c] += xv[r].y + bo4[r];
    Ct[(t4 + 2) * 257 + c] += xv[r].z + bo4[r];
    Ct[(t4 + 3) * 257 + c] += xv[r].w + bo4[r];
  }
  __syncthreads();
  #pragma unroll
  for (int rr = 0; rr < 4; ++rr) {
    int t = (w << 2) + rr;
    float v[4];
    float sum = 0.f, sq = 0.f;
    #pragma unroll
    for (int j = 0; j < 4; ++j) {
      v[j] = Ct[t * 257 + lane + 64 * j];
      sum += v[j];
      sq += v[j] * v[j];
    }
    #pragma unroll
    for (int m = 1; m < 64; m <<= 1) {
      sum += __shfl_xor(sum, m);
      sq += __shfl_xor(sq, m);
    }
    float mean = sum * (1.f / 256.f);
    float var = sq * (1.f / 256.f) - mean * mean;
    float rstd = rsqrtf(var + 1e-5f);
    #pragma unroll
    for (int j = 0; j < 4; ++j)
      Ct[t * 257 + lane + 64 * j] = (v[j] - mean) * rstd * g[j] + be[j];
  }
  __syncthreads();
  #pragma unroll
  for (int p = 0; p < 4; ++p) {
    int c = (p << 6) + (tid >> 3), t4 = (tid & 7) << 2;
    float4 o;
    o.x = Ct[(t4 + 0) * 257 + c];
    o.y = Ct[(t4 + 1) * 257 + c];
    o.z = Ct[(t4 + 2) * 257 + c];
    o.w = Ct[(t4 + 3) * 257 + c];
    *(float4*)&out[((size_t)(b * 256 + c)) * NPTS + t0 + t4] = o;
  }
}

extern "C" void kernel_launch(void* const* d_in, const int* in_sizes, int n_in,
                              void* d_out, int out_size, void* d_ws, size_t ws_size,
                              hipStream_t stream) {
  const float* x     = (const float*)d_in[0];
  const float* w_in  = (const float*)d_in[1];
  const float* b_in  = (const float*)d_in[2];
  const float* wconv = (const float*)d_in[3];
  const float* bconv = (const float*)d_in[4];
  const float* A_log = (const float*)d_in[5];
  const float* Dsk   = (const float*)d_in[6];
  const float* Bw    = (const float*)d_in[7];
  const float* Cw    = (const float*)d_in[8];
  const float* w_out = (const float*)d_in[9];
  const float* b_out = (const float*)d_in[10];
  const float* gamma = (const float*)d_in[11];
  const float* beta  = (const float*)d_in[12];
  float* out = (float*)d_out;

  static int s_attr = 0;
  if (!s_attr) {
    hipFuncSetAttribute(reinterpret_cast<const void*>(k_mega),
                        hipFuncAttributeMaxDynamicSharedMemorySize, SMEM_SZ);
    s_attr = 1;
  }
  k_mega<<<dim3(128, 4), 512, SMEM_SZ, stream>>>(x, w_in, b_in, wconv, bconv, A_log,
                                                 Dsk, Bw, Cw, w_out, b_out, gamma, beta, out);
}

// Round 4
// 153.978 us; speedup vs baseline: 1.0583x; 1.0583x over previous
//
#include <hip/hip_runtime.h>
#include <math.h>

#define NPTS 4096
#define LDA  264          // bf16 row stride (16B-aligned, conflict-benign)
// LDS regions (bytes)
#define S_R1  0           // bf16 [67][LDA]: xT -> x1 -> xs -> y
#define S_R3  35376       // bf16 [64][LDA]: delta ; later f32 Ct[32][257]
#define S_BML 69168       // f32 [64][20]
#define S_CML 74288       // f32 [64][20]
#define SMEM_SZ 79408

typedef __bf16 bf16x8 __attribute__((ext_vector_type(8)));
typedef __bf16 bf16x4 __attribute__((ext_vector_type(4)));
typedef float  f32x4  __attribute__((ext_vector_type(4)));
typedef float  f32x2  __attribute__((ext_vector_type(2)));

// packed fp32 (CDNA full-rate, 2 f32 per issue slot)
#define PK_MUL(d, s0, s1)  asm("v_pk_mul_f32 %0, %1, %2" : "=v"(d) : "v"(s0), "v"(s1))
#define PK_FMA(d, s0, s2)  asm("v_pk_fma_f32 %0, %1, %0, %2" : "+v"(d) : "v"(s0), "v"(s2))   // d = s0*d + s2
#define PK_FMA3(d, s0, s1) asm("v_pk_fma_f32 %0, %1, %2, %0" : "+v"(d) : "v"(s0), "v"(s1))   // d += s0*s1

__device__ __forceinline__ float sigmoidf_(float v) {
  return __fdividef(1.f, 1.f + __expf(-v));
}
__device__ __forceinline__ f32x2 lo2(float4 v) { f32x2 r; r[0] = v.x; r[1] = v.y; return r; }
__device__ __forceinline__ f32x2 hi2(float4 v) { f32x2 r; r[0] = v.z; r[1] = v.w; return r; }

// ===== K0: one-shot fp32->bf16 for w_in, w_out, Bw, Cw
__global__ __launch_bounds__(256) void k_prep(const float* __restrict__ w_in,
                                              const float* __restrict__ w_out,
                                              const float* __restrict__ Bw,
                                              const float* __restrict__ Cw,
                                              __bf16* __restrict__ wbi,
                                              __bf16* __restrict__ wbo,
                                              __bf16* __restrict__ wbB,
                                              __bf16* __restrict__ wbC) {
  int i = blockIdx.x * 256 + threadIdx.x;   // float4 index, 51200 total
  const float* src; __bf16* dst; int off;
  if (i < 32768)      { src = w_in;  dst = wbi; off = i; }
  else if (i < 49152) { src = w_out; dst = wbo; off = i - 32768; }
  else if (i < 50176) { src = Bw;    dst = wbB; off = i - 49152; }
  else                { src = Cw;    dst = wbC; off = i - 50176; }
  float4 v = *(const float4*)&src[off << 2];
  bf16x4 p;
  p[0] = (__bf16)v.x; p[1] = (__bf16)v.y; p[2] = (__bf16)v.z; p[3] = (__bf16)v.w;
  *(bf16x4*)&dst[off << 2] = p;
}

// ===== fused kernel: grid (128, 4), 1024 threads (16 waves), 79.4 KB dyn LDS.
// 2 blocks/CU = 32 waves/CU (needs VGPR <= 64, hence thin per-wave tiles).
__global__ __launch_bounds__(1024, 8) void k_mega(const float* __restrict__ x,
                                                  const __bf16* __restrict__ wbi,
                                                  const float* __restrict__ b_in,
                                                  const float* __restrict__ wconv,
                                                  const float* __restrict__ bconv,
                                                  const float* __restrict__ A_log,
                                                  const float* __restrict__ Dsk,
                                                  const __bf16* __restrict__ wbB,
                                                  const __bf16* __restrict__ wbC,
                                                  const __bf16* __restrict__ wbo,
                                                  const float* __restrict__ b_out,
                                                  const float* __restrict__ gamma,
                                                  const float* __restrict__ beta,
                                                  float* __restrict__ out) {
  extern __shared__ unsigned char smem[];
  __bf16* R1  = (__bf16*)(smem + S_R1);
  __bf16* bdt = (__bf16*)(smem + S_R3);
  float*  Bml = (float*) (smem + S_BML);
  float*  Cml = (float*) (smem + S_CML);
  float*  Ct  = (float*) (smem + S_R3);   // aliases bdt (dead after scan)

  const int tid = threadIdx.x, lane = tid & 63, w = tid >> 6;   // w: 0..15
  const int b = blockIdx.y, t0 = blockIdx.x << 5;
  const int mrow = lane & 15, klane = (lane >> 4) << 3;
  const int r4 = (lane >> 4) << 2;

  // ---- per-thread constants for scan (4 states per thread)
  const int ds = tid >> 2, sq = (tid & 3) << 2;
  f32x2 a01, a23;
  {
    float4 A0 = *(const float4*)&A_log[(ds << 4) + sq];
    a01[0] = -__expf(A0.x); a01[1] = -__expf(A0.y);
    a23[0] = -__expf(A0.z); a23[1] = -__expf(A0.w);
  }
  const float Dv = Dsk[ds];

  // ---- P1: transpose x[b, :, t0-35 .. t0+31] -> R1 rows 0..66 (row i <-> t = t0-35+i)
  {
    const int c = tid >> 2, q = tid & 3;
    const size_t xrow = (size_t)(b * 256 + c) * NPTS;
    #pragma unroll
    for (int g = 0; g < 4; ++g) {
      int fg = (q << 2) + g;                 // float4 group 0..15
      int t = t0 - 32 + (fg << 2);
      float4 v = make_float4(0.f, 0.f, 0.f, 0.f);
      if (t >= 0) v = *(const float4*)&x[xrow + t];
      int i0 = 3 + (fg << 2);
      R1[(i0 + 0) * LDA + c] = (__bf16)v.x;
      R1[(i0 + 1) * LDA + c] = (__bf16)v.y;
      R1[(i0 + 2) * LDA + c] = (__bf16)v.z;
      R1[(i0 + 3) * LDA + c] = (__bf16)v.w;
    }
    if (tid < 256) {   // head rows 0..2 (t = t0-35..t0-33)
      int t = t0 - 36;
      float4 v = make_float4(0.f, 0.f, 0.f, 0.f);
      if (t >= 0) v = *(const float4*)&x[(size_t)(b * 256 + tid) * NPTS + t];
      R1[0 * LDA + tid] = (__bf16)v.y;
      R1[1 * LDA + tid] = (__bf16)v.z;
      R1[2 * LDA + tid] = (__bf16)v.w;
    }
  }
  // pre-issue P2's first weight tile (global, independent of LDS) before the barrier
  const __bf16* wZ = &wbi[(size_t)(256 + (w << 4) + mrow) * 256 + klane];
  bf16x8 zv = *(const bf16x8*)&wZ[0];
  __syncthreads();

  // ---- P2: delta = sigmoid(Wz.x + bz): wave w owns m-tile (channels w*16..w*16+15)
  {
    f32x4 acc[4] = {};
    for (int k0 = 0; k0 < 256; k0 += 32) {
      bf16x8 af = zv;
      int kn = (k0 + 32) & 255;
      zv = *(const bf16x8*)&wZ[kn];
      #pragma unroll
      for (int ni = 0; ni < 4; ++ni) {
        bf16x8 bx = *(bf16x8*)&R1[(3 + (ni << 4) + mrow) * LDA + k0 + klane];
        acc[ni] = __builtin_amdgcn_mfma_f32_16x16x32_bf16(af, bx, acc[ni], 0, 0, 0);
      }
    }
    int d = (w << 4) + r4;
    float4 bi = *(const float4*)&b_in[256 + d];
    float bia[4] = {bi.x, bi.y, bi.z, bi.w};
    #pragma unroll
    for (int ni = 0; ni < 4; ++ni) {
      int j = (ni << 4) + mrow;                 // row j <-> t = t0-32+j
      bool ok = (t0 - 32 + j) >= 0;
      bf16x4 p;
      #pragma unroll
      for (int rg = 0; rg < 4; ++rg)
        p[rg] = ok ? (__bf16)sigmoidf_(acc[ni][rg] + bia[rg]) : (__bf16)0.f;
      *(bf16x4*)&bdt[j * LDA + d] = p;
    }
  }

  // ---- P3: x1 = Wx.x + bx: wave w owns m-tile; 5 n-tiles {0,16,32,48,51}
  {
    const __bf16* wX = &wbi[(size_t)((w << 4) + mrow) * 256 + klane];
    bf16x8 xv8 = *(const bf16x8*)&wX[0];
    f32x4 acc[5] = {};
    const int n0s[5] = {0, 16, 32, 48, 51};
    for (int k0 = 0; k0 < 256; k0 += 32) {
      bf16x8 af = xv8;
      int kn = (k0 + 32) & 255;
      xv8 = *(const bf16x8*)&wX[kn];
      #pragma unroll
      for (int ni = 0; ni < 5; ++ni) {
        bf16x8 bx = *(bf16x8*)&R1[(n0s[ni] + mrow) * LDA + k0 + klane];
        acc[ni] = __builtin_amdgcn_mfma_f32_16x16x32_bf16(af, bx, acc[ni], 0, 0, 0);
      }
    }
    __syncthreads();   // all xT reads done -> R1 writable
    int d = (w << 4) + r4;
    float4 bi = *(const float4*)&b_in[d];
    float bia[4] = {bi.x, bi.y, bi.z, bi.w};
    #pragma unroll
    for (int ni = 0; ni < 5; ++ni) {
      int i = n0s[ni] + mrow;                   // rows 51..63 double-written, same value
      bool ok = (t0 - 35 + i) >= 0;
      bf16x4 p;
      #pragma unroll
      for (int rg = 0; rg < 4; ++rg) {
        float v = acc[ni][rg] + bia[rg];
        p[rg] = ok ? (__bf16)v : (__bf16)0.f;
      }
      *(bf16x4*)&R1[i * LDA + d] = p;
    }
  }
  __syncthreads();

  // pre-issue P5's first B/C weight tile (waves 0..7 only) before the conv phase
  const int mat = w & 1, n0bc = (w >> 1) << 4;
  const __bf16* WrBC = (mat ? wbC : wbB) + mrow * 256 + klane;
  bf16x8 wv = {};
  if (w < 8) wv = *(const bf16x8*)&WrBC[0];

  // ---- P4: conv + silu in place, 4 segments of 16 rows per channel
  {
    const int d = tid & 255, seg = tid >> 8;     // seg 0..3
    const int j0 = seg << 4;
    const float4 wc = *(const float4*)&wconv[d << 2];
    const float bcv = bconv[d];
    float m3 = (float)R1[(j0 + 0) * LDA + d];
    float m2 = (float)R1[(j0 + 1) * LDA + d];
    float m1 = (float)R1[(j0 + 2) * LDA + d];
    float xc_n = (float)R1[(j0 + 3) * LDA + d];
    float d0 = 0.f, d1 = 0.f, d2 = 0.f;   // segs 1..3 defer rows j0..j0+2 (seam race)
    #pragma unroll
    for (int i2 = 0; i2 < 16; ++i2) {
      float xc = xc_n;
      xc_n = (float)R1[(j0 + (i2 == 15 ? 18 : i2 + 4)) * LDA + d];  // folds at compile time
      float cv = fmaf(wc.x, m3, fmaf(wc.y, m2, fmaf(wc.z, m1, fmaf(wc.w, xc, bcv))));
      float sv = cv * sigmoidf_(cv);
      if (seg && i2 == 0)      d0 = sv;
      else if (seg && i2 == 1) d1 = sv;
      else if (seg && i2 == 2) d2 = sv;
      else R1[(j0 + i2) * LDA + d] = (__bf16)sv;
      m3 = m2; m2 = m1; m1 = xc;
    }
    __syncthreads();
    if (seg) {
      R1[(j0 + 0) * LDA + d] = (__bf16)d0;
      R1[(j0 + 1) * LDA + d] = (__bf16)d1;
      R1[(j0 + 2) * LDA + d] = (__bf16)d2;
    }
  }
  __syncthreads();

  // ---- P5: B/C projection, waves 0..7 (w&1 = B/C, w>>1 = n-tile); waves 8..15 idle
  if (w < 8) {
    f32x4 accb = {};
    for (int k0 = 0; k0 < 256; k0 += 32) {
      bf16x8 av = wv;
      int kn = (k0 + 32) & 255;
      wv = *(const bf16x8*)&WrBC[kn];
      bf16x8 bv = *(bf16x8*)&R1[(n0bc + mrow) * LDA + k0 + klane];
      accb = __builtin_amdgcn_mfma_f32_16x16x32_bf16(av, bv, accb, 0, 0, 0);
    }
    float* dst = mat ? Cml : Bml;           // D: row=m=s, col=n=t
    int j = n0bc + mrow;
    #pragma unroll
    for (int rg = 0; rg < 4; ++rg)
      dst[j * 20 + r4 + rg] = accb[rg];
  }
  // pre-issue P7's first w_out tile before the scan
  const __bf16* wO = &wbo[(size_t)((w << 4) + mrow) * 256 + klane];
  bf16x8 ov = *(const bf16x8*)&wO[0];
  __syncthreads();

  // ---- P6: scan — 32 warm steps (h only), 32 live steps (y -> R1), packed f32
  f32x2 h01 = {0.f, 0.f}, h23 = {0.f, 0.f};
  float u_n = (float)bdt[0 * LDA + ds];
  float4 bv_n = *(float4*)&Bml[0 * 20 + sq];
  #pragma unroll
  for (int j = 0; j < 32; ++j) {
    float u = u_n; float4 bv = bv_n;
    u_n = (float)bdt[(j + 1) * LDA + ds];          // j+1 <= 32: valid row
    bv_n = *(float4*)&Bml[(j + 1) * 20 + sq];
    f32x2 u2; u2[0] = u; u2[1] = u;
    f32x2 t;
    PK_MUL(t, u2, lo2(bv)); PK_FMA(h01, a01, t);
    PK_MUL(t, u2, hi2(bv)); PK_FMA(h23, a23, t);
  }
  {
    float4 cv_n = *(float4*)&Cml[32 * 20 + sq];
    #pragma unroll
    for (int j = 32; j < 64; ++j) {
      float u = u_n; float4 bv = bv_n, cv = cv_n;
      int jn = (j + 1) & 63;                       // j=63 wraps to row 0 (harmless)
      u_n = (float)bdt[jn * LDA + ds];
      bv_n = *(float4*)&Bml[jn * 20 + sq];
      cv_n = *(float4*)&Cml[jn * 20 + sq];
      f32x2 u2; u2[0] = u; u2[1] = u;
      f32x2 t, pa;
      PK_MUL(t, u2, lo2(bv)); PK_FMA(h01, a01, t);
      PK_MUL(t, u2, hi2(bv)); PK_FMA(h23, a23, t);
      PK_MUL(pa, h01, lo2(cv)); PK_FMA3(pa, h23, hi2(cv));
      float yv = pa[0] + pa[1];
      yv += __shfl_xor(yv, 1);
      yv += __shfl_xor(yv, 2);
      if ((tid & 3) == 0) {
        float xv = (float)R1[j * LDA + ds];
        R1[j * LDA + ds] = (__bf16)fmaf(Dv, xv, yv);
      }
    }
  }
  __syncthreads();

  // ---- P7: out_proj MFMA on y (R1 rows 32..63) -> Ct (aliases dead bdt)
  float4 xv[2]; float bo2[2];
  {
    f32x4 acc2[2] = {};
    for (int k0 = 0; k0 < 256; k0 += 32) {
      bf16x8 af = ov;
      int kn = (k0 + 32) & 255;
      ov = *(const bf16x8*)&wO[kn];
      bf16x8 bx0 = *(bf16x8*)&R1[(32 + mrow) * LDA + k0 + klane];
      bf16x8 bx1 = *(bf16x8*)&R1[(48 + mrow) * LDA + k0 + klane];
      acc2[0] = __builtin_amdgcn_mfma_f32_16x16x32_bf16(af, bx0, acc2[0], 0, 0, 0);
      acc2[1] = __builtin_amdgcn_mfma_f32_16x16x32_bf16(af, bx1, acc2[1], 0, 0, 0);
    }
    // issue the residual x-gather early: lands while Ct is being written
    #pragma unroll
    for (int r = 0; r < 2; ++r) {
      int idx = (r << 10) + tid;
      int c = idx >> 3, t4 = (idx & 7) << 2;
      xv[r] = *(const float4*)&x[((size_t)(b * 256 + c)) * NPTS + t0 + t4];
      bo2[r] = b_out[c];
    }
    const int o0w = w << 4;
    #pragma unroll
    for (int ni = 0; ni < 2; ++ni) {
      int t = (ni << 4) + mrow;
      int o = o0w + r4;
      #pragma unroll
      for (int rg = 0; rg < 4; ++rg)
        Ct[t * 257 + o + rg] = acc2[ni][rg];
    }
  }
  __syncthreads();

  // ---- P8: residual + bias, LayerNorm over C, transposed store
  #pragma unroll
  for (int r = 0; r < 2; ++r) {
    int idx = (r << 10) + tid;
    int c = idx >> 3, t4 = (idx & 7) << 2;
    Ct[(t4 + 0) * 257 + c] += xv[r].x + bo2[r];
    Ct[(t4 + 1) * 257 + c] += xv[r].y + bo2[r];
    Ct[(t4 + 2) * 257 + c] += xv[r].z + bo2[r];
    Ct[(t4 + 3) * 257 + c] += xv[r].w + bo2[r];
  }
  float g[4], be[4];
  #pragma unroll
  for (int j = 0; j < 4; ++j) {
    g[j]  = gamma[lane + 64 * j];
    be[j] = beta[lane + 64 * j];
  }
  __syncthreads();
  #pragma unroll
  for (int rr = 0; rr < 2; ++rr) {
    int t = (w << 1) + rr;
    float v[4];
    float sum = 0.f, sq2 = 0.f;
    #pragma unroll
    for (int j = 0; j < 4; ++j) {
      v[j] = Ct[t * 257 + lane + 64 * j];
      sum += v[j];
      sq2 += v[j] * v[j];
    }
    #pragma unroll
    for (int m = 1; m < 64; m <<= 1) {
      sum += __shfl_xor(sum, m);
      sq2 += __shfl_xor(sq2, m);
    }
    float mean = sum * (1.f / 256.f);
    float var = sq2 * (1.f / 256.f) - mean * mean;
    float rstd = rsqrtf(var + 1e-5f);
    #pragma unroll
    for (int j = 0; j < 4; ++j)
      Ct[t * 257 + lane + 64 * j] = (v[j] - mean) * rstd * g[j] + be[j];
  }
  __syncthreads();
  #pragma unroll
  for (int p = 0; p < 2; ++p) {
    int idx = (p << 10) + tid;
    int c = idx >> 3, t4 = (idx & 7) << 2;
    float4 o;
    o.x = Ct[(t4 + 0) * 257 + c];
    o.y = Ct[(t4 + 1) * 257 + c];
    o.z = Ct[(t4 + 2) * 257 + c];
    o.w = Ct[(t4 + 3) * 257 + c];
    *(float4*)&out[((size_t)(b * 256 + c)) * NPTS + t0 + t4] = o;
  }
}

extern "C" void kernel_launch(void* const* d_in, const int* in_sizes, int n_in,
                              void* d_out, int out_size, void* d_ws, size_t ws_size,
                              hipStream_t stream) {
  const float* x     = (const float*)d_in[0];
  const float* w_in  = (const float*)d_in[1];
  const float* b_in  = (const float*)d_in[2];
  const float* wconv = (const float*)d_in[3];
  const float* bconv = (const float*)d_in[4];
  const float* A_log = (const float*)d_in[5];
  const float* Dsk   = (const float*)d_in[6];
  const float* Bw    = (const float*)d_in[7];
  const float* Cw    = (const float*)d_in[8];
  const float* w_out = (const float*)d_in[9];
  const float* b_out = (const float*)d_in[10];
  const float* gamma = (const float*)d_in[11];
  const float* beta  = (const float*)d_in[12];
  float* ws = (float*)d_ws;
  __bf16* wbi = (__bf16*)(ws + 0);        // [512][256]
  __bf16* wbo = (__bf16*)(ws + 65536);    // [256][256]
  __bf16* wbB = (__bf16*)(ws + 98304);    // [16][256]
  __bf16* wbC = (__bf16*)(ws + 100352);   // [16][256]
  float* out = (float*)d_out;

  static int s_attr = 0;
  if (!s_attr) {
    hipFuncSetAttribute(reinterpret_cast<const void*>(k_mega),
                        hipFuncAttributeMaxDynamicSharedMemorySize, SMEM_SZ);
    s_attr = 1;
  }
  k_prep<<<200, 256, 0, stream>>>(w_in, w_out, Bw, Cw, wbi, wbo, wbB, wbC);
  k_mega<<<dim3(128, 4), 1024, SMEM_SZ, stream>>>(x, wbi, b_in, wconv, bconv, A_log,
                                                  Dsk, wbB, wbC, wbo, b_out, gamma, beta, out);
}

// Round 6
// 141.324 us; speedup vs baseline: 1.1530x; 1.0895x over previous
//
#include <hip/hip_runtime.h>
#include <math.h>

#define NPTS 4096
#define LDA  264          // bf16 row stride (16B-aligned, conflict-benign)
// LDS regions (bytes) — shared layout for both kernels
#define S_R1  0           // A: bf16 [35][LDA] xT->x1->xs ; B: bf16 [32][LDA] xs->y
#define S_DT  18480       // bf16 [32][LDA] delta rows
#define S_BML 35376       // f32 [32][20]
#define S_CML 37936       // f32 [32][20]
#define SMEM_SZ 40496
// B only: Ct f32 [32][257] = 32896 B aliases S_R1..(R1+bdt dead after P7 k-loop)

typedef __bf16 bf16x8 __attribute__((ext_vector_type(8)));
typedef __bf16 bf16x4 __attribute__((ext_vector_type(4)));
typedef float  f32x4  __attribute__((ext_vector_type(4)));
typedef float  f32x2  __attribute__((ext_vector_type(2)));

// packed fp32 (CDNA full-rate, 2 f32 per issue slot)
#define PK_MUL(d, s0, s1)  asm("v_pk_mul_f32 %0, %1, %2" : "=v"(d) : "v"(s0), "v"(s1))
#define PK_FMA(d, s0, s2)  asm("v_pk_fma_f32 %0, %1, %0, %2" : "+v"(d) : "v"(s0), "v"(s2))   // d = s0*d + s2
#define PK_FMA3(d, s0, s1) asm("v_pk_fma_f32 %0, %1, %2, %0" : "+v"(d) : "v"(s0), "v"(s1))   // d += s0*s1

__device__ __forceinline__ float sigmoidf_(float v) {
  return __fdividef(1.f, 1.f + __expf(-v));
}
__device__ __forceinline__ f32x2 lo2(float4 v) { f32x2 r; r[0] = v.x; r[1] = v.y; return r; }
__device__ __forceinline__ f32x2 hi2(float4 v) { f32x2 r; r[0] = v.z; r[1] = v.w; return r; }

// ===== K0: one-shot fp32->bf16 for w_in, w_out, Bw, Cw
__global__ __launch_bounds__(256) void k_prep(const float* __restrict__ w_in,
                                              const float* __restrict__ w_out,
                                              const float* __restrict__ Bw,
                                              const float* __restrict__ Cw,
                                              __bf16* __restrict__ wbi,
                                              __bf16* __restrict__ wbo,
                                              __bf16* __restrict__ wbB,
                                              __bf16* __restrict__ wbC) {
  int i = blockIdx.x * 256 + threadIdx.x;   // float4 index, 51200 total
  const float* src; __bf16* dst; int off;
  if (i < 32768)      { src = w_in;  dst = wbi; off = i; }
  else if (i < 49152) { src = w_out; dst = wbo; off = i - 32768; }
  else if (i < 50176) { src = Bw;    dst = wbB; off = i - 49152; }
  else                { src = Cw;    dst = wbC; off = i - 50176; }
  float4 v = *(const float4*)&src[off << 2];
  bf16x4 p;
  p[0] = (__bf16)v.x; p[1] = (__bf16)v.y; p[2] = (__bf16)v.z; p[3] = (__bf16)v.w;
  *(bf16x4*)&dst[off << 2] = p;
}

// ===== Kernel A: per chunk (no warm-up): transpose -> in_proj -> conv -> B/C proj
// -> E-pass scan. Stages delta/xs/B/C/E to workspace for kernel B.
__global__ __launch_bounds__(512, 4) void k_partA(const float* __restrict__ x,
                                                  const __bf16* __restrict__ wbi,
                                                  const float* __restrict__ b_in,
                                                  const float* __restrict__ wconv,
                                                  const float* __restrict__ bconv,
                                                  const float* __restrict__ A_log,
                                                  const __bf16* __restrict__ wbB,
                                                  const __bf16* __restrict__ wbC,
                                                  __bf16* __restrict__ dG,
                                                  __bf16* __restrict__ xsG,
                                                  float* __restrict__ BGg,
                                                  float* __restrict__ CGg,
                                                  float* __restrict__ E) {
  extern __shared__ unsigned char smem[];
  __bf16* R1  = (__bf16*)(smem + S_R1);
  __bf16* bdt = (__bf16*)(smem + S_DT);
  float*  Bml = (float*) (smem + S_BML);
  float*  Cml = (float*) (smem + S_CML);

  const int tid = threadIdx.x, lane = tid & 63, w = tid >> 6;
  const int b = blockIdx.y, cx = blockIdx.x, t0 = cx << 5;
  const int mrow = lane & 15, klane = (lane >> 4) << 3;
  const int r4 = (lane >> 4) << 2;
  const int ds = tid >> 1, sh = (tid & 1) << 3;

  // scan decay constants (only a needed in A)
  f32x2 a01, a23, a45, a67;
  {
    float4 A0 = *(const float4*)&A_log[(ds << 4) + sh];
    float4 A1 = *(const float4*)&A_log[(ds << 4) + sh + 4];
    a01[0] = -__expf(A0.x); a01[1] = -__expf(A0.y);
    a23[0] = -__expf(A0.z); a23[1] = -__expf(A0.w);
    a45[0] = -__expf(A1.x); a45[1] = -__expf(A1.y);
    a67[0] = -__expf(A1.z); a67[1] = -__expf(A1.w);
  }

  // ---- P1: transpose x[b, :, t0-3 .. t0+31] -> R1 rows 0..34 (row i <-> t = t0-3+i)
  {
    const int c = tid >> 1;
    const size_t xrow = (size_t)(b * 256 + c) * NPTS;
    #pragma unroll
    for (int r = 0; r < 4; ++r) {
      int fg = (tid & 1) + (r << 1);
      int t = t0 + (fg << 2);
      float4 v = *(const float4*)&x[xrow + t];
      int i0 = 3 + (fg << 2);
      R1[(i0 + 0) * LDA + c] = (__bf16)v.x;
      R1[(i0 + 1) * LDA + c] = (__bf16)v.y;
      R1[(i0 + 2) * LDA + c] = (__bf16)v.z;
      R1[(i0 + 3) * LDA + c] = (__bf16)v.w;
    }
    if (tid < 256) {   // head rows 0..2 (t = t0-3..t0-1)
      int t = t0 - 4;
      float4 v = make_float4(0.f, 0.f, 0.f, 0.f);
      if (t >= 0) v = *(const float4*)&x[(size_t)(b * 256 + tid) * NPTS + t];
      R1[0 * LDA + tid] = (__bf16)v.y;
      R1[1 * LDA + tid] = (__bf16)v.z;
      R1[2 * LDA + tid] = (__bf16)v.w;
    }
  }
  // pre-issue P2's first weight tiles before the barrier
  const __bf16* wZ0 = &wbi[(size_t)(256 + (w << 5) + mrow) * 256 + klane];
  const __bf16* wZ1 = wZ0 + 16 * 256;
  bf16x8 z0v = *(const bf16x8*)&wZ0[0];
  bf16x8 z1v = *(const bf16x8*)&wZ1[0];
  __syncthreads();

  // ---- P2: delta = sigmoid(Wz.x + bz): n-tiles {3,19} -> bdt rows 0..31
  {
    f32x4 acc[2][2] = {};
    for (int k0 = 0; k0 < 256; k0 += 32) {
      bf16x8 af0 = z0v, af1 = z1v;
      int kn = (k0 + 32) & 255;
      z0v = *(const bf16x8*)&wZ0[kn];
      z1v = *(const bf16x8*)&wZ1[kn];
      #pragma unroll
      for (int ni = 0; ni < 2; ++ni) {
        bf16x8 bx = *(bf16x8*)&R1[(3 + (ni << 4) + mrow) * LDA + k0 + klane];
        acc[0][ni] = __builtin_amdgcn_mfma_f32_16x16x32_bf16(af0, bx, acc[0][ni], 0, 0, 0);
        acc[1][ni] = __builtin_amdgcn_mfma_f32_16x16x32_bf16(af1, bx, acc[1][ni], 0, 0, 0);
      }
    }
    #pragma unroll
    for (int mi = 0; mi < 2; ++mi) {
      int d = (w << 5) + (mi << 4) + r4;
      float4 bi = *(const float4*)&b_in[256 + d];
      float bia[4] = {bi.x, bi.y, bi.z, bi.w};
      #pragma unroll
      for (int ni = 0; ni < 2; ++ni) {
        int j = (ni << 4) + mrow;
        bf16x4 p;
        #pragma unroll
        for (int rg = 0; rg < 4; ++rg)
          p[rg] = (__bf16)sigmoidf_(acc[mi][ni][rg] + bia[rg]);
        *(bf16x4*)&bdt[j * LDA + d] = p;
      }
    }
  }

  // ---- P3: x1 = Wx.x + bx -> R1 in place; n-tiles {0,16,19}
  {
    const __bf16* wX0 = &wbi[(size_t)((w << 5) + mrow) * 256 + klane];
    const __bf16* wX1 = wX0 + 16 * 256;
    bf16x8 x0v = *(const bf16x8*)&wX0[0];
    bf16x8 x1v = *(const bf16x8*)&wX1[0];
    f32x4 acc[2][3] = {};
    const int n0s[3] = {0, 16, 19};
    for (int k0 = 0; k0 < 256; k0 += 32) {
      bf16x8 af0 = x0v, af1 = x1v;
      int kn = (k0 + 32) & 255;
      x0v = *(const bf16x8*)&wX0[kn];
      x1v = *(const bf16x8*)&wX1[kn];
      #pragma unroll
      for (int ni = 0; ni < 3; ++ni) {
        bf16x8 bx = *(bf16x8*)&R1[(n0s[ni] + mrow) * LDA + k0 + klane];
        acc[0][ni] = __builtin_amdgcn_mfma_f32_16x16x32_bf16(af0, bx, acc[0][ni], 0, 0, 0);
        acc[1][ni] = __builtin_amdgcn_mfma_f32_16x16x32_bf16(af1, bx, acc[1][ni], 0, 0, 0);
      }
    }
    __syncthreads();   // all xT reads done -> R1 writable; also orders bdt for copy below
    #pragma unroll
    for (int mi = 0; mi < 2; ++mi) {
      int d = (w << 5) + (mi << 4) + r4;
      float4 bi = *(const float4*)&b_in[d];
      float bia[4] = {bi.x, bi.y, bi.z, bi.w};
      #pragma unroll
      for (int ni = 0; ni < 3; ++ni) {
        int i = n0s[ni] + mrow;                 // rows 19..31 double-written, same value
        bool ok = (t0 - 3 + i) >= 0;            // conv zero-padding for t<0
        bf16x4 p;
        #pragma unroll
        for (int rg = 0; rg < 4; ++rg) {
          float v = acc[mi][ni][rg] + bia[rg];
          p[rg] = ok ? (__bf16)v : (__bf16)0.f;
        }
        *(bf16x4*)&R1[i * LDA + d] = p;
      }
    }
  }
  // delta -> global (bdt complete since the barrier above)
  #pragma unroll
  for (int r = 0; r < 2; ++r) {
    int idx = (r << 9) + tid;
    int row = idx >> 5, colg = (idx & 31) << 3;
    *(uint4*)&dG[((size_t)(b * NPTS + t0 + row)) * 256 + colg] =
        *(uint4*)&bdt[row * LDA + colg];
  }
  __syncthreads();

  // pre-issue P5's first B/C weight tile (waves 0..3)
  const int mat = w >> 1, n0bc = (w & 1) << 4;
  const __bf16* WrBC = (mat ? wbC : wbB) + mrow * 256 + klane;
  bf16x8 wv = {};
  if (w < 4) wv = *(const bf16x8*)&WrBC[0];

  // ---- P4: conv + silu in place (-3 stagger): out row j <-> t = t0+j
  {
    const int d = tid & 255, seg = tid >> 8;    // 2 segs x 16 rows
    const int j0 = seg << 4;
    const float4 wc = *(const float4*)&wconv[d << 2];
    const float bcv = bconv[d];
    float m3 = (float)R1[(j0 + 0) * LDA + d];
    float m2 = (float)R1[(j0 + 1) * LDA + d];
    float m1 = (float)R1[(j0 + 2) * LDA + d];
    float xc_n = (float)R1[(j0 + 3) * LDA + d];
    float d0 = 0.f, d1 = 0.f, d2 = 0.f;         // seg1 defers rows 16..18 (seam race)
    #pragma unroll
    for (int i2 = 0; i2 < 16; ++i2) {
      float xc = xc_n;
      xc_n = (float)R1[(j0 + (i2 == 15 ? 18 : i2 + 4)) * LDA + d];
      float cv = fmaf(wc.x, m3, fmaf(wc.y, m2, fmaf(wc.z, m1, fmaf(wc.w, xc, bcv))));
      float sv = cv * sigmoidf_(cv);
      if (seg && i2 == 0)      d0 = sv;
      else if (seg && i2 == 1) d1 = sv;
      else if (seg && i2 == 2) d2 = sv;
      else R1[(j0 + i2) * LDA + d] = (__bf16)sv;
      m3 = m2; m2 = m1; m1 = xc;
    }
    __syncthreads();
    if (seg) {
      R1[(j0 + 0) * LDA + d] = (__bf16)d0;
      R1[(j0 + 1) * LDA + d] = (__bf16)d1;
      R1[(j0 + 2) * LDA + d] = (__bf16)d2;
    }
  }
  __syncthreads();

  // ---- P5: B/C projection (waves 0..3) || xs -> global (waves 4..7)
  if (w < 4) {
    f32x4 accb = {};
    for (int k0 = 0; k0 < 256; k0 += 32) {
      bf16x8 av = wv;
      int kn = (k0 + 32) & 255;
      wv = *(const bf16x8*)&WrBC[kn];
      bf16x8 bv = *(bf16x8*)&R1[(n0bc + mrow) * LDA + k0 + klane];
      accb = __builtin_amdgcn_mfma_f32_16x16x32_bf16(av, bv, accb, 0, 0, 0);
    }
    float* dst = mat ? Cml : Bml;               // D: row=m=s, col=n=t
    int j = n0bc + mrow;
    #pragma unroll
    for (int rg = 0; rg < 4; ++rg)
      dst[j * 20 + r4 + rg] = accb[rg];
  } else {
    const int tid2 = tid - 256;                 // 256 threads copy 16 KB
    #pragma unroll
    for (int r = 0; r < 4; ++r) {
      int idx = (r << 8) + tid2;
      int row = idx >> 5, colg = (idx & 31) << 3;
      *(uint4*)&xsG[((size_t)(b * NPTS + t0 + row)) * 256 + colg] =
          *(uint4*)&R1[row * LDA + colg];
    }
  }
  __syncthreads();

  // B/C -> global (tiny)
  {
    int j = tid >> 4, s = tid & 15;
    size_t gi = ((size_t)(b * 128 + cx) << 9) + tid;
    BGg[gi] = Bml[j * 20 + s];
    CGg[gi] = Cml[j * 20 + s];
  }

  // ---- P6a: E-pass — 32 steps h-only from h=0; store chunk carry E
  f32x2 h01 = {0.f, 0.f}, h23 = {0.f, 0.f}, h45 = {0.f, 0.f}, h67 = {0.f, 0.f};
  {
    float u_n = (float)bdt[0 * LDA + ds];
    float4 b0_n = *(float4*)&Bml[0 * 20 + sh];
    float4 b1_n = *(float4*)&Bml[0 * 20 + sh + 4];
    #pragma unroll
    for (int j = 0; j < 32; ++j) {
      float u = u_n; float4 b0 = b0_n, b1 = b1_n;
      int jn = (j + 1) & 31;                    // wrap harmless (unused at j=31)
      u_n = (float)bdt[jn * LDA + ds];
      b0_n = *(float4*)&Bml[jn * 20 + sh];
      b1_n = *(float4*)&Bml[jn * 20 + sh + 4];
      f32x2 u2; u2[0] = u; u2[1] = u;
      f32x2 t;
      PK_MUL(t, u2, lo2(b0)); PK_FMA(h01, a01, t);
      PK_MUL(t, u2, hi2(b0)); PK_FMA(h23, a23, t);
      PK_MUL(t, u2, lo2(b1)); PK_FMA(h45, a45, t);
      PK_MUL(t, u2, hi2(b1)); PK_FMA(h67, a67, t);
    }
  }
  {
    float* Ep = E + ((size_t)(b * 128 + cx) << 12) + (ds << 4) + sh;
    float4 e0, e1;
    e0.x = h01[0]; e0.y = h01[1]; e0.z = h23[0]; e0.w = h23[1];
    e1.x = h45[0]; e1.y = h45[1]; e1.z = h67[0]; e1.w = h67[1];
    *(float4*)&Ep[0] = e0;
    *(float4*)&Ep[4] = e1;
  }
}

// ===== Kernel B: reload staged chunk, combine carry h0 from E[cx-1..cx-3],
// live scan with y, out_proj, residual+LN, store.
__global__ __launch_bounds__(512, 4) void k_partB(const float* __restrict__ x,
                                                  const float* __restrict__ A_log,
                                                  const float* __restrict__ Dsk,
                                                  const __bf16* __restrict__ wbo,
                                                  const float* __restrict__ b_out,
                                                  const float* __restrict__ gamma,
                                                  const float* __restrict__ beta,
                                                  const __bf16* __restrict__ dG,
                                                  const __bf16* __restrict__ xsG,
                                                  const float* __restrict__ BGg,
                                                  const float* __restrict__ CGg,
                                                  const float* __restrict__ E,
                                                  float* __restrict__ out) {
  extern __shared__ unsigned char smem[];
  __bf16* R1  = (__bf16*)(smem + S_R1);   // xs -> y (rows 0..31)
  __bf16* bdt = (__bf16*)(smem + S_DT);
  float*  Bml = (float*) (smem + S_BML);
  float*  Cml = (float*) (smem + S_CML);
  float*  Ct  = (float*) (smem + S_R1);   // aliases R1+bdt (dead after P7 k-loop)

  const int tid = threadIdx.x, lane = tid & 63, w = tid >> 6;
  const int b = blockIdx.y, cx = blockIdx.x, t0 = cx << 5;
  const int mrow = lane & 15, klane = (lane >> 4) << 3;
  const int r4 = (lane >> 4) << 2;
  const int ds = tid >> 1, sh = (tid & 1) << 3;

  // pre-issue first w_out tiles
  const __bf16* wO0 = &wbo[(size_t)((w << 5) + mrow) * 256 + klane];
  const __bf16* wO1 = wO0 + 16 * 256;
  bf16x8 o0v = *(const bf16x8*)&wO0[0];
  bf16x8 o1v = *(const bf16x8*)&wO1[0];

  // staging loads -> LDS (coalesced, L2-warm)
  #pragma unroll
  for (int r = 0; r < 2; ++r) {
    int idx = (r << 9) + tid;
    int row = idx >> 5, colg = (idx & 31) << 3;
    size_t gsrc = ((size_t)(b * NPTS + t0 + row)) * 256 + colg;
    *(uint4*)&bdt[row * LDA + colg] = *(const uint4*)&dG[gsrc];
    *(uint4*)&R1[row * LDA + colg]  = *(const uint4*)&xsG[gsrc];
  }
  {
    int j = tid >> 4, s = tid & 15;
    size_t gi = ((size_t)(b * 128 + cx) << 9) + tid;
    Bml[j * 20 + s] = BGg[gi];
    Cml[j * 20 + s] = CGg[gi];
  }

  // per-thread constants
  f32x2 a01, a23, a45, a67, a32_01, a32_23, a32_45, a32_67;
  {
    float4 A0 = *(const float4*)&A_log[(ds << 4) + sh];
    float4 A1 = *(const float4*)&A_log[(ds << 4) + sh + 4];
    a01[0] = -__expf(A0.x); a01[1] = -__expf(A0.y);
    a23[0] = -__expf(A0.z); a23[1] = -__expf(A0.w);
    a45[0] = -__expf(A1.x); a45[1] = -__expf(A1.y);
    a67[0] = -__expf(A1.z); a67[1] = -__expf(A1.w);
    a32_01[0] = __expf(32.f * A0.x); a32_01[1] = __expf(32.f * A0.y);
    a32_23[0] = __expf(32.f * A0.z); a32_23[1] = __expf(32.f * A0.w);
    a32_45[0] = __expf(32.f * A1.x); a32_45[1] = __expf(32.f * A1.y);
    a32_67[0] = __expf(32.f * A1.z); a32_67[1] = __expf(32.f * A1.w);
  }
  const float Dv = Dsk[ds];

  // carry combine: h0 = E[cx-1] + a32*(E[cx-2] + a32*E[cx-3]); trunc <= a^96 ~ 7e-5
  f32x2 h01, h23, h45, h67;
  {
    const float* Eb = E + ((size_t)(b * 128) << 12) + (ds << 4) + sh;
    float4 z4 = make_float4(0.f, 0.f, 0.f, 0.f);
    float4 e1a = z4, e1b = z4, e2a = z4, e2b = z4, e3a = z4, e3b = z4;
    if (cx >= 1) { e1a = *(const float4*)&Eb[(size_t)(cx - 1) << 12];
                   e1b = *(const float4*)&Eb[((size_t)(cx - 1) << 12) + 4]; }
    if (cx >= 2) { e2a = *(const float4*)&Eb[(size_t)(cx - 2) << 12];
                   e2b = *(const float4*)&Eb[((size_t)(cx - 2) << 12) + 4]; }
    if (cx >= 3) { e3a = *(const float4*)&Eb[(size_t)(cx - 3) << 12];
                   e3b = *(const float4*)&Eb[((size_t)(cx - 3) << 12) + 4]; }
    f32x2 t01 = lo2(e2a); PK_FMA3(t01, a32_01, lo2(e3a));
    f32x2 t23 = hi2(e2a); PK_FMA3(t23, a32_23, hi2(e3a));
    f32x2 t45 = lo2(e2b); PK_FMA3(t45, a32_45, lo2(e3b));
    f32x2 t67 = hi2(e2b); PK_FMA3(t67, a32_67, hi2(e3b));
    h01 = lo2(e1a); PK_FMA3(h01, a32_01, t01);
    h23 = hi2(e1a); PK_FMA3(h23, a32_23, t23);
    h45 = lo2(e1b); PK_FMA3(h45, a32_45, t45);
    h67 = hi2(e1b); PK_FMA3(h67, a32_67, t67);
  }
  __syncthreads();   // staging LDS complete

  // live scan — 32 full steps with y -> R1 in place
  {
    float u_n = (float)bdt[0 * LDA + ds];
    float4 b0_n = *(float4*)&Bml[0 * 20 + sh];
    float4 b1_n = *(float4*)&Bml[0 * 20 + sh + 4];
    float4 c0_n = *(float4*)&Cml[0 * 20 + sh];
    float4 c1_n = *(float4*)&Cml[0 * 20 + sh + 4];
    #pragma unroll
    for (int j = 0; j < 32; ++j) {
      float u = u_n; float4 b0 = b0_n, b1 = b1_n, c0 = c0_n, c1 = c1_n;
      int jn = (j + 1) & 31;
      u_n = (float)bdt[jn * LDA + ds];
      b0_n = *(float4*)&Bml[jn * 20 + sh];
      b1_n = *(float4*)&Bml[jn * 20 + sh + 4];
      c0_n = *(float4*)&Cml[jn * 20 + sh];
      c1_n = *(float4*)&Cml[jn * 20 + sh + 4];
      f32x2 u2; u2[0] = u; u2[1] = u;
      f32x2 t, pa, pb;
      PK_MUL(t, u2, lo2(b0)); PK_FMA(h01, a01, t);
      PK_MUL(t, u2, hi2(b0)); PK_FMA(h23, a23, t);
      PK_MUL(t, u2, lo2(b1)); PK_FMA(h45, a45, t);
      PK_MUL(t, u2, hi2(b1)); PK_FMA(h67, a67, t);
      PK_MUL(pa, h01, lo2(c0)); PK_FMA3(pa, h23, hi2(c0));
      PK_MUL(pb, h45, lo2(c1)); PK_FMA3(pb, h67, hi2(c1));
      float yv = pa[0] + pa[1] + pb[0] + pb[1];
      yv += __shfl_xor(yv, 1);
      if ((tid & 1) == 0) {
        float xv = (float)R1[j * LDA + ds];
        R1[j * LDA + ds] = (__bf16)fmaf(Dv, xv, yv);
      }
    }
  }
  __syncthreads();

  // P7: out_proj MFMA on y (R1 rows 0..31) -> Ct
  float4 xv[4]; float bo4[4];
  {
    f32x4 acc[2][2] = {};
    for (int k0 = 0; k0 < 256; k0 += 32) {
      bf16x8 af0 = o0v, af1 = o1v;
      int kn = (k0 + 32) & 255;
      o0v = *(const bf16x8*)&wO0[kn];
      o1v = *(const bf16x8*)&wO1[kn];
      bf16x8 bx0 = *(bf16x8*)&R1[(0 + mrow) * LDA + k0 + klane];
      bf16x8 bx1 = *(bf16x8*)&R1[(16 + mrow) * LDA + k0 + klane];
      acc[0][0] = __builtin_amdgcn_mfma_f32_16x16x32_bf16(af0, bx0, acc[0][0], 0, 0, 0);
      acc[0][1] = __builtin_amdgcn_mfma_f32_16x16x32_bf16(af0, bx1, acc[0][1], 0, 0, 0);
      acc[1][0] = __builtin_amdgcn_mfma_f32_16x16x32_bf16(af1, bx0, acc[1][0], 0, 0, 0);
      acc[1][1] = __builtin_amdgcn_mfma_f32_16x16x32_bf16(af1, bx1, acc[1][1], 0, 0, 0);
    }
    // residual x-gather issued early
    #pragma unroll
    for (int r = 0; r < 4; ++r) {
      int idx = (r << 9) + tid;
      int c = idx >> 3, t4 = (idx & 7) << 2;
      xv[r] = *(const float4*)&x[((size_t)(b * 256 + c)) * NPTS + t0 + t4];
      bo4[r] = b_out[c];
    }
    __syncthreads();   // all R1/bdt reads done -> Ct (aliasing) writable
    const int o0w = w << 5;
    #pragma unroll
    for (int mi = 0; mi < 2; ++mi)
      #pragma unroll
      for (int ni = 0; ni < 2; ++ni) {
        int t = (ni << 4) + mrow;
        int o = o0w + (mi << 4) + r4;
        #pragma unroll
        for (int rg = 0; rg < 4; ++rg)
          Ct[t * 257 + o + rg] = acc[mi][ni][rg];
      }
  }
  __syncthreads();

  // P8: residual + bias, LayerNorm over C, transposed store
  #pragma unroll
  for (int r = 0; r < 4; ++r) {
    int idx = (r << 9) + tid;
    int c = idx >> 3, t4 = (idx & 7) << 2;
    Ct[(t4 + 0) * 257 + c] += xv[r].x + bo4[r];
    Ct[(t4 + 1) * 257 + c] += xv[r].y + bo4[r];
    Ct[(t4 + 2) * 257 + c] += xv[r].z + bo4[r];
    Ct[(t4 + 3) * 257 + c] += xv[r].w + bo4[r];
  }
  float g[4], be[4];
  #pragma unroll
  for (int j = 0; j < 4; ++j) {
    g[j]  = gamma[lane + 64 * j];
    be[j] = beta[lane + 64 * j];
  }
  __syncthreads();
  #pragma unroll
  for (int rr = 0; rr < 4; ++rr) {
    int t = (w << 2) + rr;
    float v[4];
    float sum = 0.f, sq2 = 0.f;
    #pragma unroll
    for (int j = 0; j < 4; ++j) {
      v[j] = Ct[t * 257 + lane + 64 * j];
      sum += v[j];
      sq2 += v[j] * v[j];
    }
    #pragma unroll
    for (int m = 1; m < 64; m <<= 1) {
      sum += __shfl_xor(sum, m);
      sq2 += __shfl_xor(sq2, m);
    }
    float mean = sum * (1.f / 256.f);
    float var = sq2 * (1.f / 256.f) - mean * mean;
    float rstd = rsqrtf(var + 1e-5f);
    #pragma unroll
    for (int j = 0; j < 4; ++j)
      Ct[t * 257 + lane + 64 * j] = (v[j] - mean) * rstd * g[j] + be[j];
  }
  __syncthreads();
  #pragma unroll
  for (int p = 0; p < 4; ++p) {
    int c = (p << 6) + (tid >> 3), t4 = (tid & 7) << 2;
    float4 o;
    o.x = Ct[(t4 + 0) * 257 + c];
    o.y = Ct[(t4 + 1) * 257 + c];
    o.z = Ct[(t4 + 2) * 257 + c];
    o.w = Ct[(t4 + 3) * 257 + c];
    *(float4*)&out[((size_t)(b * 256 + c)) * NPTS + t0 + t4] = o;
  }
}

extern "C" void kernel_launch(void* const* d_in, const int* in_sizes, int n_in,
                              void* d_out, int out_size, void* d_ws, size_t ws_size,
                              hipStream_t stream) {
  const float* x     = (const float*)d_in[0];
  const float* w_in  = (const float*)d_in[1];
  const float* b_in  = (const float*)d_in[2];
  const float* wconv = (const float*)d_in[3];
  const float* bconv = (const float*)d_in[4];
  const float* A_log = (const float*)d_in[5];
  const float* Dsk   = (const float*)d_in[6];
  const float* Bw    = (const float*)d_in[7];
  const float* Cw    = (const float*)d_in[8];
  const float* w_out = (const float*)d_in[9];
  const float* b_out = (const float*)d_in[10];
  const float* gamma = (const float*)d_in[11];
  const float* beta  = (const float*)d_in[12];
  float* ws = (float*)d_ws;
  __bf16* wbi  = (__bf16*)(ws + 0);        // [512][256] bf16
  __bf16* wbo  = (__bf16*)(ws + 65536);    // [256][256] bf16
  __bf16* wbB  = (__bf16*)(ws + 98304);    // [16][256] bf16
  __bf16* wbC  = (__bf16*)(ws + 100352);   // [16][256] bf16
  float*  Ebuf = ws + 102400;              // f32 [4][128][4096] chunk carries (8 MB)
  __bf16* dG   = (__bf16*)(ws + 2199552);  // bf16 [4][4096][256] delta
  __bf16* xsG  = (__bf16*)(ws + 4296704);  // bf16 [4][4096][256] silu(conv)
  float*  BGg  = ws + 6393856;             // f32 [4][128][32][16]
  float*  CGg  = ws + 6656000;             // f32 [4][128][32][16]
  float* out = (float*)d_out;

  k_prep<<<200, 256, 0, stream>>>(w_in, w_out, Bw, Cw, wbi, wbo, wbB, wbC);
  k_partA<<<dim3(128, 4), 512, SMEM_SZ, stream>>>(x, wbi, b_in, wconv, bconv, A_log,
                                                  wbB, wbC, dG, xsG, BGg, CGg, Ebuf);
  k_partB<<<dim3(128, 4), 512, SMEM_SZ, stream>>>(x, A_log, Dsk, wbo, b_out, gamma, beta,
                                                  dG, xsG, BGg, CGg, Ebuf, out);
}